// Round 13
// baseline (84.062 us; speedup 1.0000x reference)
//
#include <hip/hip_runtime.h>
#include <hip/hip_fp16.h>

#define EMBED 128
#define NRBF 6
#define VOCAB 100
#define EBLOCK 1024
#define GROUPS 32                   // 32-lane groups per block
#define CPG 19                      // edges per group per half
#define HALF_E (GROUPS * CPG)       // 608
#define BCHUNK (2 * HALF_E)         // 1216
#define T_HALFS (VOCAB * EMBED)                            // 12800 halfs/table
#define TABLE_BYTES (2 * T_HALFS * 2 + NRBF * EMBED * 4)   // 54,272 B
#define SMEM_BYTES (TABLE_BYTES + HALF_E * 16)             // 64,000 B -> 2 blocks/CU

typedef float  f32x4 __attribute__((ext_vector_type(4)));
typedef float  f32x2 __attribute__((ext_vector_type(2)));
typedef int    i32x2 __attribute__((ext_vector_type(2)));

// ---------------------------------------------------------------------------
// Precompute (206 blocks): T1h/T2h fp16 tables (+bias folded in T1), Wc fp32.
//   T1h[v][d] = fp16( sum_j emb[v][j]*Wd[j][d] + b[d] )
//   T2h[v][d] = fp16( sum_j emb[v][j]*Wd[128+j][d] )
//   Wc[k][d]  = sum_j W_edge[k][j]*Wd[256+j][d]
// ---------------------------------------------------------------------------
__global__ __launch_bounds__(EMBED) void precompute_kernel(
    const float* __restrict__ W_edge,
    const float* __restrict__ emb,
    const float* __restrict__ Wd,
    const float* __restrict__ b,
    __half* __restrict__ T1h,
    __half* __restrict__ T2h,
    float* __restrict__ Wc)
{
    const int d = threadIdx.x;
    const int v = blockIdx.x;
    if (v < 2 * VOCAB) {
        const int row = (v < VOCAB) ? v : v - VOCAB;
        const int woff = (v < VOCAB) ? 0 : EMBED;
        __shared__ float hrow[EMBED];
        hrow[d] = emb[row * EMBED + d];
        __syncthreads();
        float acc = (v < VOCAB) ? b[d] : 0.0f;
        #pragma unroll 8
        for (int j = 0; j < EMBED; ++j)
            acc += hrow[j] * Wd[(woff + j) * EMBED + d];
        if (v < VOCAB) T1h[row * EMBED + d] = __float2half_rn(acc);
        else           T2h[row * EMBED + d] = __float2half_rn(acc);
    } else {
        const int k = v - 2 * VOCAB;
        float acc = 0.0f;
        #pragma unroll 8
        for (int j = 0; j < EMBED; ++j)
            acc += W_edge[k * EMBED + j] * Wd[(2 * EMBED + j) * EMBED + d];
        Wc[k * EMBED + d] = acc;
    }
}

// ---------------------------------------------------------------------------
// Edge kernel (R10 structure + cache-policy control):
//  - output stores NONTEMPORAL (no L2 allocate -> stop evicting z/tables)
//  - e_rbf/nbr stage loads NONTEMPORAL (read-once streams)
//  - z loads cached (tiny, becomes L2-resident once pollution stops)
// fp16 tables in LDS (ds_read_b64), 64 KB LDS -> 2 blocks/CU; per half:
// stage meta {6x fp16 rbf, z[a]|z[b]<<16} -> barrier -> consume with
// contiguous 1 KB wave stores (pair-mapped groups).
// ---------------------------------------------------------------------------
__global__ __launch_bounds__(EBLOCK, 8) void edge_kernel(
    const float* __restrict__ e_rbf,   // [E,6]
    const int*   __restrict__ z,       // [N]
    const int*   __restrict__ nbr,     // [E,2]
    const float* __restrict__ tables,  // T1h|T2h|Wc in ws
    float* __restrict__ out,           // [E,128]
    int E)
{
    extern __shared__ char smemraw[];
    __half* T1s  = (__half*)smemraw;                    // [12800]
    __half* T2s  = T1s + T_HALFS;                       // [12800]
    float*  Wcs  = (float*)(smemraw + 2 * T_HALFS * 2); // [768]
    uint4*  meta = (uint4*)(smemraw + TABLE_BYTES);     // [608]

    const int tid  = threadIdx.x;
    const int base = blockIdx.x * BCHUNK;
    const int lane = tid & 31;
    const int d    = lane * 4;
    const int g    = tid >> 5;

    // ---- stage tables ----
    {
        const float4* src = reinterpret_cast<const float4*>(tables);
        float4* dst = reinterpret_cast<float4*>(smemraw);
        #pragma unroll 2
        for (int i = tid; i < TABLE_BYTES / 16; i += EBLOCK)
            dst[i] = src[i];
    }

    auto stage_half = [&](int ebase) {
        if (tid < HALF_E) {
            const int e = ebase + tid;
            uint4 m = make_uint4(0u, 0u, 0u, 0u);
            if (e < E) {
                const i32x2 nn = __builtin_nontemporal_load(
                    reinterpret_cast<const i32x2*>(nbr + 2 * e));
                const float* rp = e_rbf + (long)e * NRBF;
                const f32x2 a  = __builtin_nontemporal_load(reinterpret_cast<const f32x2*>(rp + 0));
                const f32x2 bb = __builtin_nontemporal_load(reinterpret_cast<const f32x2*>(rp + 2));
                const f32x2 c  = __builtin_nontemporal_load(reinterpret_cast<const f32x2*>(rp + 4));
                __half2 ha = __float22half2_rn(make_float2(a.x, a.y));
                __half2 hb = __float22half2_rn(make_float2(bb.x, bb.y));
                __half2 hc = __float22half2_rn(make_float2(c.x, c.y));
                m.x = *reinterpret_cast<unsigned*>(&ha);
                m.y = *reinterpret_cast<unsigned*>(&hb);
                m.z = *reinterpret_cast<unsigned*>(&hc);
                m.w = (unsigned)z[nn.x] | ((unsigned)z[nn.y] << 16);   // cached
            }
            meta[tid] = m;
        }
    };

    // ---- stage half 0 ----
    stage_half(base);
    __syncthreads();

    // Wc into registers (invariant)
    const float4 wc0 = *reinterpret_cast<const float4*>(Wcs + 0 * EMBED + d);
    const float4 wc1 = *reinterpret_cast<const float4*>(Wcs + 1 * EMBED + d);
    const float4 wc2 = *reinterpret_cast<const float4*>(Wcs + 2 * EMBED + d);
    const float4 wc3 = *reinterpret_cast<const float4*>(Wcs + 3 * EMBED + d);
    const float4 wc4 = *reinterpret_cast<const float4*>(Wcs + 4 * EMBED + d);
    const float4 wc5 = *reinterpret_cast<const float4*>(Wcs + 5 * EMBED + d);

    auto consume_half = [&](int ebase) {
        const int lb = (g >> 1) * (2 * CPG) + (g & 1);   // pair-mapped
        #pragma unroll
        for (int i = 0; i < CPG; ++i) {
            const int le = lb + 2 * i;
            const int e = ebase + le;

            const uint4 m = meta[le];                    // ds_read_b128 bcast
            const int za = (int)(m.w & 0xffffu) << 7;
            const int zb = (int)(m.w >> 16) << 7;

            const uint2 t1p = *reinterpret_cast<const uint2*>(T1s + za + d);
            const uint2 t2p = *reinterpret_cast<const uint2*>(T2s + zb + d);
            const __half2 s0 = __hadd2(*reinterpret_cast<const __half2*>(&t1p.x),
                                       *reinterpret_cast<const __half2*>(&t2p.x));
            const __half2 s1 = __hadd2(*reinterpret_cast<const __half2*>(&t1p.y),
                                       *reinterpret_cast<const __half2*>(&t2p.y));
            const float2 a01 = __half22float2(s0);
            const float2 a23 = __half22float2(s1);
            float4 acc = make_float4(a01.x, a01.y, a23.x, a23.y);

            const float2 f01 = __half22float2(*reinterpret_cast<const __half2*>(&m.x));
            const float2 f23 = __half22float2(*reinterpret_cast<const __half2*>(&m.y));
            const float2 f45 = __half22float2(*reinterpret_cast<const __half2*>(&m.z));

            acc.x += f01.x * wc0.x; acc.y += f01.x * wc0.y; acc.z += f01.x * wc0.z; acc.w += f01.x * wc0.w;
            acc.x += f01.y * wc1.x; acc.y += f01.y * wc1.y; acc.z += f01.y * wc1.z; acc.w += f01.y * wc1.w;
            acc.x += f23.x * wc2.x; acc.y += f23.x * wc2.y; acc.z += f23.x * wc2.z; acc.w += f23.x * wc2.w;
            acc.x += f23.y * wc3.x; acc.y += f23.y * wc3.y; acc.z += f23.y * wc3.z; acc.w += f23.y * wc3.w;
            acc.x += f45.x * wc4.x; acc.y += f45.x * wc4.y; acc.z += f45.x * wc4.z; acc.w += f45.x * wc4.w;
            acc.x += f45.y * wc5.x; acc.y += f45.y * wc5.y; acc.z += f45.y * wc5.z; acc.w += f45.y * wc5.w;

            float4 rr;
            rr.x = acc.x * __builtin_amdgcn_rcpf(1.0f + __expf(-acc.x));
            rr.y = acc.y * __builtin_amdgcn_rcpf(1.0f + __expf(-acc.y));
            rr.z = acc.z * __builtin_amdgcn_rcpf(1.0f + __expf(-acc.z));
            rr.w = acc.w * __builtin_amdgcn_rcpf(1.0f + __expf(-acc.w));

            if (e < E) {
                // nontemporal: no L2 allocate -> stores stop evicting z/tables
                __builtin_nontemporal_store(
                    *reinterpret_cast<f32x4*>(&rr),
                    reinterpret_cast<f32x4*>(out + (long)e * EMBED + d));
            }
        }
    };

    // ---- consume half 0 ----
    consume_half(base);
    __syncthreads();

    // ---- stage + consume half 1 ----
    stage_half(base + HALF_E);
    __syncthreads();
    consume_half(base + HALF_E);
}

extern "C" void kernel_launch(void* const* d_in, const int* in_sizes, int n_in,
                              void* d_out, int out_size, void* d_ws, size_t ws_size,
                              hipStream_t stream)
{
    // Input order: e_rbf, z, nbr_list, W_edge, emb_table, W_dense, b_dense
    const float* e_rbf  = (const float*)d_in[0];
    const int*   z      = (const int*)  d_in[1];
    const int*   nbr    = (const int*)  d_in[2];
    const float* W_edge = (const float*)d_in[3];
    const float* emb    = (const float*)d_in[4];
    const float* Wd     = (const float*)d_in[5];
    const float* b      = (const float*)d_in[6];
    float* out = (float*)d_out;

    const int E = in_sizes[2] / 2;

    __half* T1h = (__half*)d_ws;
    __half* T2h = T1h + T_HALFS;
    float*  Wc  = (float*)((char*)d_ws + 2 * T_HALFS * 2);

    precompute_kernel<<<2 * VOCAB + NRBF, EMBED, 0, stream>>>(W_edge, emb, Wd, b, T1h, T2h, Wc);

    const int grid = (E + BCHUNK - 1) / BCHUNK;   // 494 for E=600000
    edge_kernel<<<grid, EBLOCK, SMEM_BYTES, stream>>>(e_rbf, z, nbr, (const float*)d_ws, out, E);
}

// Round 15
// 78.256 us; speedup vs baseline: 1.0742x; 1.0742x over previous
//
#include <hip/hip_runtime.h>
#include <hip/hip_fp16.h>

#define EMBED 128
#define NRBF 6
#define VOCAB 100
#define EBLOCK 512                  // 8 waves per block
#define GROUPS 16                   // 32-lane groups per block
#define CPG 19                      // edges per group per half
#define HALF_E (GROUPS * CPG)       // 304
#define BCHUNK (2 * HALF_E)         // 608 edges per block
#define T_HALFS (VOCAB * EMBED)                            // 12800 halfs/table
#define TABLE_BYTES (2 * T_HALFS * 2 + NRBF * EMBED * 4)   // 54,272 B
#define SMEM_BYTES (TABLE_BYTES + HALF_E * 16)             // 59,136 B -> 2 blocks/CU

// ---------------------------------------------------------------------------
// Precompute (206 blocks): T1h/T2h fp16 tables (+bias folded in T1), Wc fp32.
//   T1h[v][d] = fp16( sum_j emb[v][j]*Wd[j][d] + b[d] )
//   T2h[v][d] = fp16( sum_j emb[v][j]*Wd[128+j][d] )
//   Wc[k][d]  = sum_j W_edge[k][j]*Wd[256+j][d]
// ---------------------------------------------------------------------------
__global__ __launch_bounds__(EMBED) void precompute_kernel(
    const float* __restrict__ W_edge,
    const float* __restrict__ emb,
    const float* __restrict__ Wd,
    const float* __restrict__ b,
    __half* __restrict__ T1h,
    __half* __restrict__ T2h,
    float* __restrict__ Wc)
{
    const int d = threadIdx.x;
    const int v = blockIdx.x;
    if (v < 2 * VOCAB) {
        const int row = (v < VOCAB) ? v : v - VOCAB;
        const int woff = (v < VOCAB) ? 0 : EMBED;
        __shared__ float hrow[EMBED];
        hrow[d] = emb[row * EMBED + d];
        __syncthreads();
        float acc = (v < VOCAB) ? b[d] : 0.0f;
        #pragma unroll 8
        for (int j = 0; j < EMBED; ++j)
            acc += hrow[j] * Wd[(woff + j) * EMBED + d];
        if (v < VOCAB) T1h[row * EMBED + d] = __float2half_rn(acc);
        else           T2h[row * EMBED + d] = __float2half_rn(acc);
    } else {
        const int k = v - 2 * VOCAB;
        float acc = 0.0f;
        #pragma unroll 8
        for (int j = 0; j < EMBED; ++j)
            acc += W_edge[k * EMBED + j] * Wd[(2 * EMBED + j) * EMBED + d];
        Wc[k * EMBED + d] = acc;
    }
}

// ---------------------------------------------------------------------------
// Edge kernel — R10 structure (two-half stage/consume interleave, proven
// passing at 1024 threads in R7/R8/R10/R13), ported to 512-thread blocks:
// __launch_bounds__(512, 4) lifts the per-thread VGPR cap 64 -> 128.
// R11 probes measured VGPR_Count=32 at the old bounds: the Wc invariants
// (24 VGPR) were rematerialized from LDS every iteration and the loop could
// not pipeline. 59,136 B LDS -> 2 blocks/CU (16 waves) preserves the
// cross-block stage/store overlap.
// ---------------------------------------------------------------------------
__global__ __launch_bounds__(EBLOCK, 4) void edge_kernel(
    const float* __restrict__ e_rbf,   // [E,6]
    const int*   __restrict__ z,       // [N]
    const int*   __restrict__ nbr,     // [E,2]
    const float* __restrict__ tables,  // T1h|T2h|Wc in ws
    float* __restrict__ out,           // [E,128]
    int E)
{
    extern __shared__ char smemraw[];
    __half* T1s  = (__half*)smemraw;                    // [12800]
    __half* T2s  = T1s + T_HALFS;                       // [12800]
    float*  Wcs  = (float*)(smemraw + 2 * T_HALFS * 2); // [768]
    uint4*  meta = (uint4*)(smemraw + TABLE_BYTES);     // [304]

    const int tid  = threadIdx.x;
    const int base = blockIdx.x * BCHUNK;
    const int lane = tid & 31;
    const int d    = lane * 4;
    const int g    = tid >> 5;

    // ---- stage tables (54,272 B) ----
    {
        const float4* src = reinterpret_cast<const float4*>(tables);
        float4* dst = reinterpret_cast<float4*>(smemraw);
        #pragma unroll 2
        for (int i = tid; i < TABLE_BYTES / 16; i += EBLOCK)
            dst[i] = src[i];
    }

    auto stage_half = [&](int ebase) {
        if (tid < HALF_E) {
            const int e = ebase + tid;
            uint4 m = make_uint4(0u, 0u, 0u, 0u);
            if (e < E) {
                const int2 nn = *reinterpret_cast<const int2*>(nbr + 2 * e);
                const float* rp = e_rbf + (long)e * NRBF;
                const float2 a  = *reinterpret_cast<const float2*>(rp + 0);
                const float2 bb = *reinterpret_cast<const float2*>(rp + 2);
                const float2 c  = *reinterpret_cast<const float2*>(rp + 4);
                __half2 ha = __float22half2_rn(a);
                __half2 hb = __float22half2_rn(bb);
                __half2 hc = __float22half2_rn(c);
                m.x = *reinterpret_cast<unsigned*>(&ha);
                m.y = *reinterpret_cast<unsigned*>(&hb);
                m.z = *reinterpret_cast<unsigned*>(&hc);
                m.w = (unsigned)z[nn.x] | ((unsigned)z[nn.y] << 16);
            }
            meta[tid] = m;
        }
    };

    // ---- stage half 0 ----
    stage_half(base);
    __syncthreads();

    // Wc into registers (24 VGPR, invariant — now stays in registers)
    const float4 wc0 = *reinterpret_cast<const float4*>(Wcs + 0 * EMBED + d);
    const float4 wc1 = *reinterpret_cast<const float4*>(Wcs + 1 * EMBED + d);
    const float4 wc2 = *reinterpret_cast<const float4*>(Wcs + 2 * EMBED + d);
    const float4 wc3 = *reinterpret_cast<const float4*>(Wcs + 3 * EMBED + d);
    const float4 wc4 = *reinterpret_cast<const float4*>(Wcs + 4 * EMBED + d);
    const float4 wc5 = *reinterpret_cast<const float4*>(Wcs + 5 * EMBED + d);

    auto consume_half = [&](int ebase) {
        const int lb = (g >> 1) * (2 * CPG) + (g & 1);   // pair-mapped
        #pragma unroll
        for (int i = 0; i < CPG; ++i) {
            const int le = lb + 2 * i;
            const int e = ebase + le;

            const uint4 m = meta[le];                    // ds_read_b128 bcast
            const int za = (int)(m.w & 0xffffu) << 7;
            const int zb = (int)(m.w >> 16) << 7;

            const uint2 t1p = *reinterpret_cast<const uint2*>(T1s + za + d);
            const uint2 t2p = *reinterpret_cast<const uint2*>(T2s + zb + d);
            const __half2 s0 = __hadd2(*reinterpret_cast<const __half2*>(&t1p.x),
                                       *reinterpret_cast<const __half2*>(&t2p.x));
            const __half2 s1 = __hadd2(*reinterpret_cast<const __half2*>(&t1p.y),
                                       *reinterpret_cast<const __half2*>(&t2p.y));
            const float2 a01 = __half22float2(s0);
            const float2 a23 = __half22float2(s1);
            float4 acc = make_float4(a01.x, a01.y, a23.x, a23.y);

            const float2 f01 = __half22float2(*reinterpret_cast<const __half2*>(&m.x));
            const float2 f23 = __half22float2(*reinterpret_cast<const __half2*>(&m.y));
            const float2 f45 = __half22float2(*reinterpret_cast<const __half2*>(&m.z));

            acc.x += f01.x * wc0.x; acc.y += f01.x * wc0.y; acc.z += f01.x * wc0.z; acc.w += f01.x * wc0.w;
            acc.x += f01.y * wc1.x; acc.y += f01.y * wc1.y; acc.z += f01.y * wc1.z; acc.w += f01.y * wc1.w;
            acc.x += f23.x * wc2.x; acc.y += f23.x * wc2.y; acc.z += f23.x * wc2.z; acc.w += f23.x * wc2.w;
            acc.x += f23.y * wc3.x; acc.y += f23.y * wc3.y; acc.z += f23.y * wc3.z; acc.w += f23.y * wc3.w;
            acc.x += f45.x * wc4.x; acc.y += f45.x * wc4.y; acc.z += f45.x * wc4.z; acc.w += f45.x * wc4.w;
            acc.x += f45.y * wc5.x; acc.y += f45.y * wc5.y; acc.z += f45.y * wc5.z; acc.w += f45.y * wc5.w;

            float4 rr;
            rr.x = acc.x * __builtin_amdgcn_rcpf(1.0f + __expf(-acc.x));
            rr.y = acc.y * __builtin_amdgcn_rcpf(1.0f + __expf(-acc.y));
            rr.z = acc.z * __builtin_amdgcn_rcpf(1.0f + __expf(-acc.z));
            rr.w = acc.w * __builtin_amdgcn_rcpf(1.0f + __expf(-acc.w));

            if (e < E)
                *reinterpret_cast<float4*>(out + (long)e * EMBED + d) = rr;
        }
    };

    // ---- consume half 0 ----
    consume_half(base);
    __syncthreads();

    // ---- stage + consume half 1 ----
    stage_half(base + HALF_E);
    __syncthreads();
    consume_half(base + HALF_E);
}

extern "C" void kernel_launch(void* const* d_in, const int* in_sizes, int n_in,
                              void* d_out, int out_size, void* d_ws, size_t ws_size,
                              hipStream_t stream)
{
    // Input order: e_rbf, z, nbr_list, W_edge, emb_table, W_dense, b_dense
    const float* e_rbf  = (const float*)d_in[0];
    const int*   z      = (const int*)  d_in[1];
    const int*   nbr    = (const int*)  d_in[2];
    const float* W_edge = (const float*)d_in[3];
    const float* emb    = (const float*)d_in[4];
    const float* Wd     = (const float*)d_in[5];
    const float* b      = (const float*)d_in[6];
    float* out = (float*)d_out;

    const int E = in_sizes[2] / 2;

    __half* T1h = (__half*)d_ws;
    __half* T2h = T1h + T_HALFS;
    float*  Wc  = (float*)((char*)d_ws + 2 * T_HALFS * 2);

    precompute_kernel<<<2 * VOCAB + NRBF, EMBED, 0, stream>>>(W_edge, emb, Wd, b, T1h, T2h, Wc);

    const int grid = (E + BCHUNK - 1) / BCHUNK;   // 987 for E=600000
    edge_kernel<<<grid, EBLOCK, SMEM_BYTES, stream>>>(e_rbf, z, nbr, (const float*)d_ws, out, E);
}

// Round 16
// 75.100 us; speedup vs baseline: 1.1193x; 1.0420x over previous
//
#include <hip/hip_runtime.h>
#include <hip/hip_fp16.h>

#define EMBED 128
#define NRBF 6
#define VOCAB 100
#define EBLOCK 1024
#define GROUPS 32                   // 32-lane groups per block
#define CPG 19                      // edges per group per half
#define HALF_E (GROUPS * CPG / 2 * 2)          // 608 (16 pairs * 38)
#define BCHUNK (2 * HALF_E)                    // 1216
// tables: T1h,T2h fp16 [100][128] + Wc fp32 [6][128]
#define T_HALFS (VOCAB * EMBED)                // 12800 halfs per table
#define TABLE_BYTES (2 * T_HALFS * 2 + NRBF * EMBED * 4)   // 51200 + 3072 = 54,272
#define SMEM_BYTES (TABLE_BYTES + HALF_E * 16)             // 54,272+9,728 = 64,000

// ---------------------------------------------------------------------------
// Precompute (206 blocks):
//   T1h[v][d] = fp16( sum_j emb[v][j]*Wd[j][d] + b[d] )
//   T2h[v][d] = fp16( sum_j emb[v][j]*Wd[128+j][d] )
//   Wc[k][d]  = fp32( sum_j W_edge[k][j]*Wd[256+j][d] )
// ---------------------------------------------------------------------------
__global__ __launch_bounds__(EMBED) void precompute_kernel(
    const float* __restrict__ W_edge,
    const float* __restrict__ emb,
    const float* __restrict__ Wd,
    const float* __restrict__ b,
    __half* __restrict__ T1h,
    __half* __restrict__ T2h,
    float* __restrict__ Wc)
{
    const int d = threadIdx.x;
    const int v = blockIdx.x;
    if (v < 2 * VOCAB) {
        const int row = (v < VOCAB) ? v : v - VOCAB;
        const int woff = (v < VOCAB) ? 0 : EMBED;
        __shared__ float hrow[EMBED];
        hrow[d] = emb[row * EMBED + d];
        __syncthreads();
        float acc = (v < VOCAB) ? b[d] : 0.0f;
        #pragma unroll 8
        for (int j = 0; j < EMBED; ++j)
            acc += hrow[j] * Wd[(woff + j) * EMBED + d];
        if (v < VOCAB) T1h[row * EMBED + d] = __float2half_rn(acc);
        else           T2h[row * EMBED + d] = __float2half_rn(acc);
    } else {
        const int k = v - 2 * VOCAB;
        float acc = 0.0f;
        #pragma unroll 8
        for (int j = 0; j < EMBED; ++j)
            acc += W_edge[k * EMBED + j] * Wd[(2 * EMBED + j) * EMBED + d];
        Wc[k * EMBED + d] = acc;
    }
}

// ---------------------------------------------------------------------------
// Edge kernel (best-measured configuration, = Round-10 submission, 75.66 us).
// fp16 tables (53 KB LDS) -> ds_read_b64 table reads, 64 KB LDS total ->
// TWO blocks per CU (32 waves). Per half: threads 0..607 stage meta
// {6x fp16 rbf, z[a]|z[b]<<16}; consume loop reads meta (b128 bcast) +
// T1h/T2h (b64), fp16 add, fp32 FMA + native-silu, one contiguous 1 KB
// store per wave (pair-mapped groups).
// ---------------------------------------------------------------------------
__global__ __launch_bounds__(EBLOCK, 8) void edge_kernel(
    const float* __restrict__ e_rbf,   // [E,6]
    const int*   __restrict__ z,       // [N]
    const int*   __restrict__ nbr,     // [E,2]
    const float* __restrict__ tables,  // T1h|T2h|Wc in ws (54,272 B)
    float* __restrict__ out,           // [E,128]
    int E)
{
    extern __shared__ char smemraw[];
    __half* T1s = (__half*)smemraw;                        // [12800]
    __half* T2s = T1s + T_HALFS;                           // [12800]
    float*  Wcs = (float*)(smemraw + 2 * T_HALFS * 2);     // [768]
    uint4*  meta = (uint4*)(smemraw + TABLE_BYTES);        // [608]

    const int tid  = threadIdx.x;
    const int base = blockIdx.x * BCHUNK;
    const int lane = tid & 31;
    const int d    = lane * 4;
    const int g    = tid >> 5;

    // ---- stage tables (54,272 B as float4s) ----
    {
        const float4* src = reinterpret_cast<const float4*>(tables);
        float4* dst = reinterpret_cast<float4*>(smemraw);
        #pragma unroll 2
        for (int i = tid; i < TABLE_BYTES / 16; i += EBLOCK)
            dst[i] = src[i];
    }

    auto stage_half = [&](int ebase) {
        if (tid < HALF_E) {
            const int e = ebase + tid;
            uint4 m = make_uint4(0u, 0u, 0u, 0u);
            if (e < E) {
                const int2 nn = *reinterpret_cast<const int2*>(nbr + 2 * e);
                const float* rp = e_rbf + (long)e * NRBF;
                const float2 a  = *reinterpret_cast<const float2*>(rp + 0);
                const float2 bb = *reinterpret_cast<const float2*>(rp + 2);
                const float2 c  = *reinterpret_cast<const float2*>(rp + 4);
                __half2 ha = __float22half2_rn(a);
                __half2 hb = __float22half2_rn(bb);
                __half2 hc = __float22half2_rn(c);
                m.x = *reinterpret_cast<unsigned*>(&ha);
                m.y = *reinterpret_cast<unsigned*>(&hb);
                m.z = *reinterpret_cast<unsigned*>(&hc);
                m.w = (unsigned)z[nn.x] | ((unsigned)z[nn.y] << 16);
            }
            meta[tid] = m;
        }
    };

    // ---- stage half 0 ----
    stage_half(base);
    __syncthreads();

    // Wc into registers (24 VGPR, invariant)
    const float4 wc0 = *reinterpret_cast<const float4*>(Wcs + 0 * EMBED + d);
    const float4 wc1 = *reinterpret_cast<const float4*>(Wcs + 1 * EMBED + d);
    const float4 wc2 = *reinterpret_cast<const float4*>(Wcs + 2 * EMBED + d);
    const float4 wc3 = *reinterpret_cast<const float4*>(Wcs + 3 * EMBED + d);
    const float4 wc4 = *reinterpret_cast<const float4*>(Wcs + 4 * EMBED + d);
    const float4 wc5 = *reinterpret_cast<const float4*>(Wcs + 5 * EMBED + d);

    auto consume_half = [&](int ebase) {
        const int lb = (g >> 1) * (2 * CPG) + (g & 1);   // pair-mapped
        #pragma unroll
        for (int i = 0; i < CPG; ++i) {
            const int le = lb + 2 * i;
            const int e = ebase + le;

            const uint4 m = meta[le];                    // ds_read_b128 bcast
            const int za = (int)(m.w & 0xffffu) << 7;
            const int zb = (int)(m.w >> 16) << 7;

            // fp16 table reads (ds_read_b64) + packed fp16 add
            const uint2 t1p = *reinterpret_cast<const uint2*>(T1s + za + d);
            const uint2 t2p = *reinterpret_cast<const uint2*>(T2s + zb + d);
            const __half2 s0 = __hadd2(*reinterpret_cast<const __half2*>(&t1p.x),
                                       *reinterpret_cast<const __half2*>(&t2p.x));
            const __half2 s1 = __hadd2(*reinterpret_cast<const __half2*>(&t1p.y),
                                       *reinterpret_cast<const __half2*>(&t2p.y));
            const float2 a01 = __half22float2(s0);
            const float2 a23 = __half22float2(s1);
            float4 acc = make_float4(a01.x, a01.y, a23.x, a23.y);

            const float2 f01 = __half22float2(*reinterpret_cast<const __half2*>(&m.x));
            const float2 f23 = __half22float2(*reinterpret_cast<const __half2*>(&m.y));
            const float2 f45 = __half22float2(*reinterpret_cast<const __half2*>(&m.z));

            acc.x += f01.x * wc0.x; acc.y += f01.x * wc0.y; acc.z += f01.x * wc0.z; acc.w += f01.x * wc0.w;
            acc.x += f01.y * wc1.x; acc.y += f01.y * wc1.y; acc.z += f01.y * wc1.z; acc.w += f01.y * wc1.w;
            acc.x += f23.x * wc2.x; acc.y += f23.x * wc2.y; acc.z += f23.x * wc2.z; acc.w += f23.x * wc2.w;
            acc.x += f23.y * wc3.x; acc.y += f23.y * wc3.y; acc.z += f23.y * wc3.z; acc.w += f23.y * wc3.w;
            acc.x += f45.x * wc4.x; acc.y += f45.x * wc4.y; acc.z += f45.x * wc4.z; acc.w += f45.x * wc4.w;
            acc.x += f45.y * wc5.x; acc.y += f45.y * wc5.y; acc.z += f45.y * wc5.z; acc.w += f45.y * wc5.w;

            float4 rr;
            rr.x = acc.x * __builtin_amdgcn_rcpf(1.0f + __expf(-acc.x));
            rr.y = acc.y * __builtin_amdgcn_rcpf(1.0f + __expf(-acc.y));
            rr.z = acc.z * __builtin_amdgcn_rcpf(1.0f + __expf(-acc.z));
            rr.w = acc.w * __builtin_amdgcn_rcpf(1.0f + __expf(-acc.w));

            if (e < E)
                *reinterpret_cast<float4*>(out + (long)e * EMBED + d) = rr;
        }
    };

    // ---- consume half 0 ----
    consume_half(base);
    __syncthreads();

    // ---- stage + consume half 1 ----
    stage_half(base + HALF_E);
    __syncthreads();
    consume_half(base + HALF_E);
}

extern "C" void kernel_launch(void* const* d_in, const int* in_sizes, int n_in,
                              void* d_out, int out_size, void* d_ws, size_t ws_size,
                              hipStream_t stream)
{
    // Input order: e_rbf, z, nbr_list, W_edge, emb_table, W_dense, b_dense
    const float* e_rbf  = (const float*)d_in[0];
    const int*   z      = (const int*)  d_in[1];
    const int*   nbr    = (const int*)  d_in[2];
    const float* W_edge = (const float*)d_in[3];
    const float* emb    = (const float*)d_in[4];
    const float* Wd     = (const float*)d_in[5];
    const float* b      = (const float*)d_in[6];
    float* out = (float*)d_out;

    const int E = in_sizes[2] / 2;

    // ws layout: T1h (12800 half) | T2h (12800 half) | Wc (768 float)
    __half* T1h = (__half*)d_ws;
    __half* T2h = T1h + T_HALFS;
    float*  Wc  = (float*)((char*)d_ws + 2 * T_HALFS * 2);

    precompute_kernel<<<2 * VOCAB + NRBF, EMBED, 0, stream>>>(W_edge, emb, Wd, b, T1h, T2h, Wc);

    const int grid = (E + BCHUNK - 1) / BCHUNK;   // 494 for E=600000
    edge_kernel<<<grid, EBLOCK, SMEM_BYTES, stream>>>(e_rbf, z, nbr, (const float*)d_ws, out, E);
}